// Round 1
// baseline (135.638 us; speedup 1.0000x reference)
//
#include <hip/hip_runtime.h>
#include <stdint.h>

// GraphCut fused contrastive loss, MI355X (gfx950).
// loss = -mean_i( sum_{j!=i} sign_ij * exp(sim_ij - rowmax_i) ),
//   sim = (F F^T)/0.2, sign = +1 same label, -1 diff, 0 diag.
// Fused flash-style: 32-row blocks sweep column tiles with bf16 MFMA
// 32x32x16; per-lane online (m, signed-sum) state; m initialized to the
// row self-dot so the exp path is skipped for ~all tiles (fp32 exp of
// (dot - m)/T underflows below dot - m < -21).

#define M_ROWS 8192
#define K_DIM  128
#define CHUNKS 4
#define COLS_PER_CHUNK (M_ROWS / CHUNKS)   // 2048
#define COLS_PER_WAVE  (COLS_PER_CHUNK / 4) // 512 -> 16 tiles of 32
#define INV_T_LOG2E 7.213475204444817f      // (1/0.2) * log2(e)

typedef __bf16 bf16x8 __attribute__((ext_vector_type(8)));
typedef float  f32x16 __attribute__((ext_vector_type(16)));

// ---- prep: fp32 -> bf16 (RNE), per-row self-dot (of rounded values), zero out ----
__global__ __launch_bounds__(256) void prep_kernel(const float* __restrict__ f,
                                                   unsigned short* __restrict__ fbf,
                                                   float* __restrict__ selfdot,
                                                   float* __restrict__ out) {
    const int row  = blockIdx.x * 4 + (threadIdx.x >> 6);
    const int lane = threadIdx.x & 63;
    const float2 v = *(const float2*)(f + (size_t)row * K_DIM + lane * 2);
    uint32_t u0 = __builtin_bit_cast(uint32_t, v.x);
    uint32_t u1 = __builtin_bit_cast(uint32_t, v.y);
    uint32_t r0 = (u0 + 0x7FFFu + ((u0 >> 16) & 1u)) >> 16;
    uint32_t r1 = (u1 + 0x7FFFu + ((u1 >> 16) & 1u)) >> 16;
    ushort2 st; st.x = (unsigned short)r0; st.y = (unsigned short)r1;
    *(ushort2*)(fbf + (size_t)row * K_DIM + lane * 2) = st;
    float b0 = __builtin_bit_cast(float, r0 << 16);
    float b1 = __builtin_bit_cast(float, r1 << 16);
    float ss = b0 * b0 + b1 * b1;
#pragma unroll
    for (int off = 1; off < 64; off <<= 1) ss += __shfl_xor(ss, off, 64);
    if (lane == 0) selfdot[row] = ss;
    if (blockIdx.x == 0 && threadIdx.x == 0) out[0] = 0.f;  // d_out is poisoned 0xAA
}

// ---- main fused kernel ----
// grid = 256 row-blocks * 4 column chunks = 1024 blocks of 256 threads.
// chunk = blk & 3 so each XCD (blk % 8) touches exactly one 0.5 MB chunk of B.
__global__ __launch_bounds__(256) void fused_kernel(const unsigned short* __restrict__ fbf,
                                                    const int* __restrict__ labels,
                                                    const float* __restrict__ selfdot,
                                                    float* __restrict__ partials) {
    const int blk   = blockIdx.x;
    const int rb    = blk >> 2;
    const int chunk = blk & 3;
    const int wave  = threadIdx.x >> 6;
    const int lane  = threadIdx.x & 63;
    const int lm    = lane & 31;
    const int l5    = lane >> 5;
    const int row0  = rb * 32;

    // A fragments resident for whole kernel: A[m = lm][k = 8*l5 + 16*s8 + j]
    bf16x8 afrag[8];
    {
        const bf16x8* ap = (const bf16x8*)(fbf + (size_t)(row0 + lm) * K_DIM + 8 * l5);
#pragma unroll
        for (int s8 = 0; s8 < 8; ++s8) afrag[s8] = ap[2 * s8];
    }

    // This lane's 16 accumulator rows (C/D layout: row = (r&3)+8*(r>>2)+4*l5)
    int gr[16]; int rowlab[16];
    float m[16], s[16];
    float minm = 1e30f;
#pragma unroll
    for (int r = 0; r < 16; ++r) {
        gr[r]     = row0 + (r & 3) + 8 * (r >> 2) + 4 * l5;
        rowlab[r] = labels[gr[r]];
        m[r]      = selfdot[gr[r]];   // diag dot: >= every off-diag dot in practice
        s[r]      = 0.f;
        minm      = fminf(minm, m[r]);
    }

    const int c0 = chunk * COLS_PER_CHUNK + wave * COLS_PER_WAVE;
    for (int it = 0; it < COLS_PER_WAVE / 32; ++it) {
        const int j = c0 + it * 32 + lm;                  // this lane's column
        const bf16x8* bp = (const bf16x8*)(fbf + (size_t)j * K_DIM + 8 * l5);
        bf16x8 bfrag[8];
#pragma unroll
        for (int s8 = 0; s8 < 8; ++s8) bfrag[s8] = bp[2 * s8];
        f32x16 acc;
#pragma unroll
        for (int r = 0; r < 16; ++r) acc[r] = 0.f;
#pragma unroll
        for (int s8 = 0; s8 < 8; ++s8)
            acc = __builtin_amdgcn_mfma_f32_32x32x16_bf16(afrag[s8], bfrag[s8], acc, 0, 0, 0);

        // wave-uniform skip: exp((dot-m)/T) == 0 in fp32 when dot - m < -21
        float amax = acc[0];
#pragma unroll
        for (int r = 1; r < 16; ++r) amax = fmaxf(amax, acc[r]);
        if (__any(amax > minm - 22.f)) {
            const int labj = labels[j];
#pragma unroll
            for (int r = 0; r < 16; ++r) {
                float d    = acc[r] - m[r];
                float sign = (labj == rowlab[r]) ? 1.f : -1.f;
                if (j == gr[r]) sign = 0.f;               // mask diagonal
                bool  p = d > 0.f;
                float e = exp2f(fminf(d, -d) * INV_T_LOG2E);  // exp(-|d|/T)
                float x = p ? s[r] : sign;
                float y = p ? sign : s[r];
                s[r] = fmaf(x, e, y);                     // online rescale-or-add
                m[r] = fmaxf(m[r], acc[r]);
            }
            minm = m[0];
#pragma unroll
            for (int r = 1; r < 16; ++r) minm = fminf(minm, m[r]);
        }
    }

    // merge the 32 per-lane column-partials of each row (butterfly in the half)
#pragma unroll
    for (int off = 1; off < 32; off <<= 1) {
#pragma unroll
        for (int r = 0; r < 16; ++r) {
            float mo = __shfl_xor(m[r], off, 64);
            float so = __shfl_xor(s[r], off, 64);
            float d  = mo - m[r];
            bool  p  = d > 0.f;
            float e  = exp2f(fminf(d, -d) * INV_T_LOG2E);
            s[r] = p ? fmaf(s[r], e, so) : fmaf(so, e, s[r]);
            m[r] = fmaxf(m[r], mo);
        }
    }
    if (lm == 0) {
        float* base = partials + ((size_t)(blk * 4 + wave) * 32) * 2;
#pragma unroll
        for (int r = 0; r < 16; ++r) {
            int rl = (r & 3) + 8 * (r >> 2) + 4 * l5;
            base[rl * 2 + 0] = m[r];
            base[rl * 2 + 1] = s[r];
        }
    }
}

// ---- merge 16 partials per row, reduce, atomic add ----
__global__ __launch_bounds__(256) void merge_kernel(const float* __restrict__ partials,
                                                    float* __restrict__ out) {
    const int g  = blockIdx.x * 256 + threadIdx.x;   // row id 0..8191
    const int rb = g >> 5;
    const int rl = g & 31;
    float M = -1e30f, S = 0.f;
#pragma unroll
    for (int c = 0; c < 4; ++c) {
#pragma unroll
        for (int w = 0; w < 4; ++w) {
            const float* p = partials + ((size_t)((rb * 4 + c) * 4 + w) * 32 + rl) * 2;
            float mo = p[0], so = p[1];
            float d  = mo - M;
            bool  pr = d > 0.f;
            float e  = exp2f(fminf(d, -d) * INV_T_LOG2E);
            S = pr ? fmaf(S, e, so) : fmaf(so, e, S);
            M = fmaxf(M, mo);
        }
    }
    float val = -S * (1.0f / 8192.0f);
#pragma unroll
    for (int off = 1; off < 64; off <<= 1) val += __shfl_xor(val, off, 64);
    __shared__ float red[4];
    if ((threadIdx.x & 63) == 0) red[threadIdx.x >> 6] = val;
    __syncthreads();
    if (threadIdx.x == 0) atomicAdd(out, red[0] + red[1] + red[2] + red[3]);
}

extern "C" void kernel_launch(void* const* d_in, const int* in_sizes, int n_in,
                              void* d_out, int out_size, void* d_ws, size_t ws_size,
                              hipStream_t stream) {
    const float* feat   = (const float*)d_in[0];
    const int*   labels = (const int*)d_in[1];
    float*       out    = (float*)d_out;
    char*        ws     = (char*)d_ws;

    unsigned short* fbf     = (unsigned short*)ws;                               // 2 MB bf16 features
    float*          selfdot = (float*)(ws + (size_t)M_ROWS * K_DIM * 2);         // 32 KB
    float*          partials= (float*)(ws + (size_t)M_ROWS * K_DIM * 2 + M_ROWS * 4); // 1 MB

    prep_kernel<<<M_ROWS / 4, 256, 0, stream>>>(feat, fbf, selfdot, out);
    fused_kernel<<<(M_ROWS / 32) * CHUNKS, 256, 0, stream>>>(fbf, labels, selfdot, partials);
    merge_kernel<<<M_ROWS / 256, 256, 0, stream>>>(partials, out);
}